// Round 1
// baseline (304.421 us; speedup 1.0000x reference)
//
#include <hip/hip_runtime.h>
#include <math.h>

#define BB 32
#define LL 2048
#define CC 1280
#define HH 160

// ---------------- Kernel 1: partial mean/max pooling over L-chunks ----------------
// grid: (lchunks, B), block: 320 threads; thread t handles channels [4t, 4t+4)
__global__ __launch_bounds__(320) void pool_partial_k(
    const float* __restrict__ x, float* __restrict__ psum,
    float* __restrict__ pmax, int lsteps) {
  const int lc = blockIdx.x;
  const int b  = blockIdx.y;
  const int c4 = threadIdx.x << 2;

  const float* xp = x + ((size_t)b * LL + (size_t)lc * lsteps) * CC + c4;
  float4 s = make_float4(0.f, 0.f, 0.f, 0.f);
  float4 m = make_float4(-INFINITY, -INFINITY, -INFINITY, -INFINITY);

#pragma unroll 4
  for (int l = 0; l < lsteps; ++l) {
    float4 v = *reinterpret_cast<const float4*>(xp + (size_t)l * CC);
    s.x += v.x; s.y += v.y; s.z += v.z; s.w += v.w;
    m.x = fmaxf(m.x, v.x); m.y = fmaxf(m.y, v.y);
    m.z = fmaxf(m.z, v.z); m.w = fmaxf(m.w, v.w);
  }
  const size_t o = ((size_t)lc * BB + b) * CC + c4;
  *reinterpret_cast<float4*>(psum + o) = s;
  *reinterpret_cast<float4*>(pmax + o) = m;
}

// ---------------- Kernel 2: finish pools + 2-layer MLP + sigmoid -> attn[B,C] ----------------
// grid: (B), block: 512 threads
__global__ __launch_bounds__(512) void mlp_attn_k(
    const float* __restrict__ psum, const float* __restrict__ pmax,
    const float* __restrict__ w1, const float* __restrict__ b1,
    const float* __restrict__ w2, const float* __restrict__ b2,
    float* __restrict__ attn, int lchunks) {
  __shared__ float gap[CC];
  __shared__ float gmp[CC];
  __shared__ float h1s[HH];
  __shared__ float h2s[HH];

  const int b = blockIdx.x;
  const int t = threadIdx.x;

  // finish the pooling reduction
  for (int c = t; c < CC; c += 512) {
    float s = 0.f, m = -INFINITY;
    for (int lc = 0; lc < lchunks; ++lc) {
      const size_t o = ((size_t)lc * BB + b) * CC + c;
      s += psum[o];
      m = fmaxf(m, pmax[o]);
    }
    gap[c] = s * (1.0f / (float)LL);
    gmp[c] = m;
  }
  __syncthreads();

  // layer 1: h1 = relu(gap@w1 + b1), h2 = relu(gmp@w1 + b1)
  if (t < 2 * HH) {
    const float* v = (t < HH) ? gap : gmp;
    const int h = (t < HH) ? t : (t - HH);
    float acc = b1[h];
#pragma unroll 8
    for (int c = 0; c < CC; ++c) acc = fmaf(v[c], w1[c * HH + h], acc);
    acc = fmaxf(acc, 0.f);
    if (t < HH) h1s[h] = acc; else h2s[h] = acc;
  }
  __syncthreads();

  // layer 2: attn = sigmoid((h1+h2)@w2 + 2*b2)
  for (int c = t; c < CC; c += 512) {
    float acc = 2.0f * b2[c];
#pragma unroll 8
    for (int h = 0; h < HH; ++h) acc = fmaf(h1s[h] + h2s[h], w2[h * CC + c], acc);
    attn[(size_t)b * CC + c] = 1.0f / (1.0f + expf(-acc));
  }
}

// ---------------- Kernel 3: out = x * attn (broadcast over L) ----------------
// grid: (B*L), block: 320 threads; thread t handles one float4 of the row
__global__ __launch_bounds__(320) void apply_k(
    const float* __restrict__ x, const float* __restrict__ attn,
    float* __restrict__ out) {
  const size_t row = blockIdx.x;          // b*L + l
  const int b = (int)(row >> 11);         // L = 2048
  const int c4 = threadIdx.x << 2;
  const size_t base = row * CC + c4;

  float4 v = *reinterpret_cast<const float4*>(x + base);
  float4 a = *reinterpret_cast<const float4*>(attn + (size_t)b * CC + c4);
  float4 o;
  o.x = v.x * a.x; o.y = v.y * a.y; o.z = v.z * a.z; o.w = v.w * a.w;
  *reinterpret_cast<float4*>(out + base) = o;
}

extern "C" void kernel_launch(void* const* d_in, const int* in_sizes, int n_in,
                              void* d_out, int out_size, void* d_ws, size_t ws_size,
                              hipStream_t stream) {
  const float* x  = (const float*)d_in[0];
  const float* w1 = (const float*)d_in[1];
  const float* b1 = (const float*)d_in[2];
  const float* w2 = (const float*)d_in[3];
  const float* b2 = (const float*)d_in[4];
  float* out = (float*)d_out;
  float* ws  = (float*)d_ws;

  // workspace layout: psum[lchunks][B][C], pmax[lchunks][B][C], attn[B][C]
  int lchunks = 16;
  while (lchunks > 1 &&
         ((size_t)lchunks * BB * CC * 2 + (size_t)BB * CC) * sizeof(float) > ws_size)
    lchunks >>= 1;
  const int lsteps = LL / lchunks;

  float* psum = ws;
  float* pmax = psum + (size_t)lchunks * BB * CC;
  float* attn = pmax + (size_t)lchunks * BB * CC;

  pool_partial_k<<<dim3(lchunks, BB), 320, 0, stream>>>(x, psum, pmax, lsteps);
  mlp_attn_k<<<BB, 512, 0, stream>>>(psum, pmax, w1, b1, w2, b2, attn, lchunks);
  apply_k<<<BB * LL, 320, 0, stream>>>(x, attn, out);
}

// Round 2
// 252.626 us; speedup vs baseline: 1.2050x; 1.2050x over previous
//
#include <hip/hip_runtime.h>
#include <math.h>

#define BB 32
#define LL 2048
#define CC 1280
#define HH 160
#define LCH 32           // L-chunks for pool partials
#define LST (LL / LCH)   // 64 L-steps per chunk

// ---------------- Kernel 1: partial mean/max pooling over L-chunks ----------------
// grid: (LCH, B), block: 320 threads; thread t handles channels [4t, 4t+4)
__global__ __launch_bounds__(320) void pool_partial_k(
    const float* __restrict__ x, float* __restrict__ psum,
    float* __restrict__ pmax) {
  const int lc = blockIdx.x;
  const int b  = blockIdx.y;
  const int c4 = threadIdx.x << 2;

  const float* xp = x + ((size_t)b * LL + (size_t)lc * LST) * CC + c4;
  float4 s = make_float4(0.f, 0.f, 0.f, 0.f);
  float4 m = make_float4(-INFINITY, -INFINITY, -INFINITY, -INFINITY);

#pragma unroll 8
  for (int l = 0; l < LST; ++l) {
    float4 v = *reinterpret_cast<const float4*>(xp + (size_t)l * CC);
    s.x += v.x; s.y += v.y; s.z += v.z; s.w += v.w;
    m.x = fmaxf(m.x, v.x); m.y = fmaxf(m.y, v.y);
    m.z = fmaxf(m.z, v.z); m.w = fmaxf(m.w, v.w);
  }
  const size_t o = ((size_t)lc * BB + b) * CC + c4;
  *reinterpret_cast<float4*>(psum + o) = s;
  *reinterpret_cast<float4*>(pmax + o) = m;
}

// ---------------- Kernel 2: finish pools -> gg[64][C] (rows 0..31 gap, 32..63 gmp) ----------------
// grid: (B, 2), block: 256
__global__ __launch_bounds__(256) void finish_pool_k(
    const float* __restrict__ psum, const float* __restrict__ pmax,
    float* __restrict__ gg) {
  const int b = blockIdx.x;
  const int ismax = blockIdx.y;
  const float* src = ismax ? pmax : psum;

  for (int c = threadIdx.x; c < CC; c += 256) {
    if (!ismax) {
      float s = 0.f;
      for (int lc = 0; lc < LCH; ++lc)
        s += src[((size_t)lc * BB + b) * CC + c];
      gg[(size_t)b * CC + c] = s * (1.0f / (float)LL);
    } else {
      float m = -INFINITY;
      for (int lc = 0; lc < LCH; ++lc)
        m = fmaxf(m, src[((size_t)lc * BB + b) * CC + c]);
      gg[(size_t)(b + BB) * CC + c] = m;
    }
  }
}

// ---------------- Kernel 3: layer 1 — hout[64][H] = relu(gg @ w1 + b1) ----------------
// grid: (H/32 htiles, 64 rows), block: 256 = 32 h_local x 8 c-slices
__global__ __launch_bounds__(256) void layer1_k(
    const float* __restrict__ gg, const float* __restrict__ w1,
    const float* __restrict__ b1, float* __restrict__ hout) {
  __shared__ float v[CC];
  __shared__ float part[8][32];

  const int r  = blockIdx.y;
  const int ht = blockIdx.x;
  const int t  = threadIdx.x;
  const int hl = t & 31;
  const int s  = t >> 5;
  const int h  = ht * 32 + hl;

  for (int c = t; c < CC; c += 256) v[c] = gg[(size_t)r * CC + c];
  __syncthreads();

  float acc = 0.f;
  const int c0 = s * (CC / 8);  // 160 channels per slice
#pragma unroll 8
  for (int k = 0; k < CC / 8; ++k)
    acc = fmaf(v[c0 + k], w1[(size_t)(c0 + k) * HH + h], acc);
  part[s][hl] = acc;
  __syncthreads();

  if (t < 32) {
    float a = part[0][t] + part[1][t] + part[2][t] + part[3][t] +
              part[4][t] + part[5][t] + part[6][t] + part[7][t] +
              b1[ht * 32 + t];
    hout[(size_t)r * HH + ht * 32 + t] = fmaxf(a, 0.f);
  }
}

// ---------------- Kernel 4: layer 2 + sigmoid -> attn[B][C] ----------------
// grid: (C/256 ctiles, B), block: 256
__global__ __launch_bounds__(256) void layer2_k(
    const float* __restrict__ hout, const float* __restrict__ w2,
    const float* __restrict__ b2, float* __restrict__ attn) {
  __shared__ float u[HH];
  const int b  = blockIdx.y;
  const int ct = blockIdx.x;
  const int t  = threadIdx.x;

  if (t < HH)
    u[t] = hout[(size_t)b * HH + t] + hout[(size_t)(b + BB) * HH + t];
  __syncthreads();

  const int c = ct * 256 + t;
  float acc = 2.0f * b2[c];
#pragma unroll 8
  for (int h = 0; h < HH; ++h)
    acc = fmaf(u[h], w2[(size_t)h * CC + c], acc);
  attn[(size_t)b * CC + c] = 1.0f / (1.0f + expf(-acc));
}

// ---------------- Kernel 5: out = x * attn (8 rows per block, attn in regs) ----------------
// grid: (B*L/8), block: 320
__global__ __launch_bounds__(320) void apply_k(
    const float* __restrict__ x, const float* __restrict__ attn,
    float* __restrict__ out) {
  const size_t r0 = (size_t)blockIdx.x * 8;   // first row (b*L + l), 8 | 2048 so same b
  const int b = (int)(r0 >> 11);              // L = 2048
  const int c4 = threadIdx.x << 2;

  const float4 a = *reinterpret_cast<const float4*>(attn + (size_t)b * CC + c4);
  const float* xp = x + r0 * CC + c4;
  float* op = out + r0 * CC + c4;

#pragma unroll
  for (int i = 0; i < 8; ++i) {
    float4 v = *reinterpret_cast<const float4*>(xp + (size_t)i * CC);
    float4 o;
    o.x = v.x * a.x; o.y = v.y * a.y; o.z = v.z * a.z; o.w = v.w * a.w;
    *reinterpret_cast<float4*>(op + (size_t)i * CC) = o;
  }
}

extern "C" void kernel_launch(void* const* d_in, const int* in_sizes, int n_in,
                              void* d_out, int out_size, void* d_ws, size_t ws_size,
                              hipStream_t stream) {
  const float* x  = (const float*)d_in[0];
  const float* w1 = (const float*)d_in[1];
  const float* b1 = (const float*)d_in[2];
  const float* w2 = (const float*)d_in[3];
  const float* b2 = (const float*)d_in[4];
  float* out = (float*)d_out;
  float* ws  = (float*)d_ws;

  // ws layout: psum[LCH][B][C], pmax[LCH][B][C], gg[64][C], hout[64][H], attn[B][C]
  float* psum = ws;
  float* pmax = psum + (size_t)LCH * BB * CC;
  float* gg   = pmax + (size_t)LCH * BB * CC;
  float* hout = gg   + (size_t)2 * BB * CC;
  float* attn = hout + (size_t)2 * BB * HH;

  pool_partial_k<<<dim3(LCH, BB), 320, 0, stream>>>(x, psum, pmax);
  finish_pool_k<<<dim3(BB, 2), 256, 0, stream>>>(psum, pmax, gg);
  layer1_k<<<dim3(HH / 32, 2 * BB), 256, 0, stream>>>(gg, w1, b1, hout);
  layer2_k<<<dim3(CC / 256, BB), 256, 0, stream>>>(hout, w2, b2, attn);
  apply_k<<<BB * LL / 8, 320, 0, stream>>>(x, attn, out);
}

// Round 3
// 238.143 us; speedup vs baseline: 1.2783x; 1.0608x over previous
//
#include <hip/hip_runtime.h>
#include <math.h>

#define BB 32
#define LL 2048
#define CC 1280
#define HH 160
#define LCH 32           // L-chunks for pool partials
#define LST (LL / LCH)   // 64 L-steps per chunk

typedef float f4 __attribute__((ext_vector_type(4)));

// ---------------- Kernel 1: partial mean/max pooling over L-chunks ----------------
// grid: (LCH, B) -> sweeps x front-to-back in dispatch order; block: 320 threads
__global__ __launch_bounds__(320) void pool_partial_k(
    const float* __restrict__ x, float* __restrict__ psum,
    float* __restrict__ pmax) {
  const int lc = blockIdx.x;
  const int b  = blockIdx.y;
  const int c4 = threadIdx.x << 2;

  const float* xp = x + ((size_t)b * LL + (size_t)lc * LST) * CC + c4;
  float4 s = make_float4(0.f, 0.f, 0.f, 0.f);
  float4 m = make_float4(-INFINITY, -INFINITY, -INFINITY, -INFINITY);

#pragma unroll 8
  for (int l = 0; l < LST; ++l) {
    float4 v = *reinterpret_cast<const float4*>(xp + (size_t)l * CC);
    s.x += v.x; s.y += v.y; s.z += v.z; s.w += v.w;
    m.x = fmaxf(m.x, v.x); m.y = fmaxf(m.y, v.y);
    m.z = fmaxf(m.z, v.z); m.w = fmaxf(m.w, v.w);
  }
  const size_t o = ((size_t)lc * BB + b) * CC + c4;
  *reinterpret_cast<float4*>(psum + o) = s;
  *reinterpret_cast<float4*>(pmax + o) = m;
}

// ---------------- Kernel 2: finish pools + layer 1 fused ----------------
// grid: 64 blocks (r<32: gap row b=r; r>=32: gmp row b=r-32), block: 320
// hout[r][h] = relu(v_r @ w1 + b1)
__global__ __launch_bounds__(320) void finish_l1_k(
    const float* __restrict__ psum, const float* __restrict__ pmax,
    const float* __restrict__ w1, const float* __restrict__ b1,
    float* __restrict__ hout) {
  __shared__ float v[CC];
  __shared__ float part[HH];

  const int r = blockIdx.x;
  const int t = threadIdx.x;
  const int b = r & (BB - 1);
  const bool ismax = (r >= BB);

  // finish the pooling reduction into LDS
  for (int c = t; c < CC; c += 320) {
    if (!ismax) {
      float s = 0.f;
      for (int lc = 0; lc < LCH; ++lc)
        s += psum[((size_t)lc * BB + b) * CC + c];
      v[c] = s * (1.0f / (float)LL);
    } else {
      float m = -INFINITY;
      for (int lc = 0; lc < LCH; ++lc)
        m = fmaxf(m, pmax[((size_t)lc * BB + b) * CC + c]);
      v[c] = m;
    }
  }
  __syncthreads();

  // layer 1: 2-way split dot (threads 0..159 -> k in [0,640), 160..319 -> [640,1280))
  const int h  = (t < HH) ? t : t - HH;
  const int k0 = (t < HH) ? 0 : CC / 2;
  float acc = 0.f;
#pragma unroll 8
  for (int k = 0; k < CC / 2; ++k)
    acc = fmaf(v[k0 + k], w1[(size_t)(k0 + k) * HH + h], acc);
  if (t >= HH) part[h] = acc;
  __syncthreads();
  if (t < HH) {
    float a = acc + part[t] + b1[t];
    hout[(size_t)r * HH + t] = fmaxf(a, 0.f);
  }
}

// ---------------- Kernel 3: layer 2 + sigmoid -> attn[B][C] ----------------
// grid: (C/256 ctiles, B), block: 256
__global__ __launch_bounds__(256) void layer2_k(
    const float* __restrict__ hout, const float* __restrict__ w2,
    const float* __restrict__ b2, float* __restrict__ attn) {
  __shared__ float u[HH];
  const int b  = blockIdx.y;
  const int ct = blockIdx.x;
  const int t  = threadIdx.x;

  if (t < HH)
    u[t] = hout[(size_t)b * HH + t] + hout[(size_t)(b + BB) * HH + t];
  __syncthreads();

  const int c = ct * 256 + t;
  float acc = 2.0f * b2[c];
#pragma unroll 8
  for (int h = 0; h < HH; ++h)
    acc = fmaf(u[h], w2[(size_t)h * CC + c], acc);
  attn[(size_t)b * CC + c] = 1.0f / (1.0f + expf(-acc));
}

// ---------------- Kernel 4: out = x * attn ----------------
// REVERSE block order: first blocks read the tail of x, which the pool pass
// left resident in the 256MB L3. Non-temporal stores keep out's write stream
// from evicting that residue.
// grid: (B*L/8), block: 320; 8 rows per block, attn row in regs
__global__ __launch_bounds__(320) void apply_k(
    const float* __restrict__ x, const float* __restrict__ attn,
    float* __restrict__ out) {
  const size_t r0 = (size_t)(gridDim.x - 1 - blockIdx.x) * 8;  // 8 | 2048 -> same b
  const int b = (int)(r0 >> 11);  // L = 2048
  const int c4 = threadIdx.x << 2;

  const f4 a = *reinterpret_cast<const f4*>(attn + (size_t)b * CC + c4);
  const float* xp = x + r0 * CC + c4;
  float* op = out + r0 * CC + c4;

#pragma unroll
  for (int i = 0; i < 8; ++i) {
    f4 v = *reinterpret_cast<const f4*>(xp + (size_t)i * CC);
    f4 o = v * a;
    __builtin_nontemporal_store(o, reinterpret_cast<f4*>(op + (size_t)i * CC));
  }
}

extern "C" void kernel_launch(void* const* d_in, const int* in_sizes, int n_in,
                              void* d_out, int out_size, void* d_ws, size_t ws_size,
                              hipStream_t stream) {
  const float* x  = (const float*)d_in[0];
  const float* w1 = (const float*)d_in[1];
  const float* b1 = (const float*)d_in[2];
  const float* w2 = (const float*)d_in[3];
  const float* b2 = (const float*)d_in[4];
  float* out = (float*)d_out;
  float* ws  = (float*)d_ws;

  // ws layout: psum[LCH][B][C], pmax[LCH][B][C], hout[64][H], attn[B][C]
  float* psum = ws;
  float* pmax = psum + (size_t)LCH * BB * CC;
  float* hout = pmax + (size_t)LCH * BB * CC;
  float* attn = hout + (size_t)2 * BB * HH;

  pool_partial_k<<<dim3(LCH, BB), 320, 0, stream>>>(x, psum, pmax);
  finish_l1_k<<<2 * BB, 320, 0, stream>>>(psum, pmax, w1, b1, hout);
  layer2_k<<<dim3(CC / 256, BB), 256, 0, stream>>>(hout, w2, b2, attn);
  apply_k<<<BB * LL / 8, 320, 0, stream>>>(x, attn, out);
}

// Round 4
// 215.079 us; speedup vs baseline: 1.4154x; 1.1072x over previous
//
#include <hip/hip_runtime.h>
#include <hip/hip_fp16.h>
#include <math.h>

#define BB 32
#define LL 2048
#define CC 1280
#define HH 160
#define LCH 32           // L-chunks for pool partials
#define LST (LL / LCH)   // 64 L-steps per chunk

typedef float f4 __attribute__((ext_vector_type(4)));
typedef _Float16 h4 __attribute__((ext_vector_type(4)));

// ---------------- Kernel 1a: pool partials + fp16 shadow copy of x ----------------
// grid: (LCH, B), block: 320. x read with NT loads (read-once, don't pollute L3);
// x_h written with normal stores (allocate -> stays resident in 256MB L3).
__global__ __launch_bounds__(320) void pool_conv_k(
    const float* __restrict__ x, float* __restrict__ psum,
    float* __restrict__ pmax, _Float16* __restrict__ xh) {
  const int lc = blockIdx.x;
  const int b  = blockIdx.y;
  const int c4 = threadIdx.x << 2;

  const size_t rowbase = ((size_t)b * LL + (size_t)lc * LST) * CC + c4;
  const float* xp = x + rowbase;
  _Float16* hp = xh + rowbase;

  f4 s = {0.f, 0.f, 0.f, 0.f};
  f4 m = {-INFINITY, -INFINITY, -INFINITY, -INFINITY};

#pragma unroll 8
  for (int l = 0; l < LST; ++l) {
    f4 v = __builtin_nontemporal_load(reinterpret_cast<const f4*>(xp + (size_t)l * CC));
    s += v;
    m.x = fmaxf(m.x, v.x); m.y = fmaxf(m.y, v.y);
    m.z = fmaxf(m.z, v.z); m.w = fmaxf(m.w, v.w);
    *reinterpret_cast<h4*>(hp + (size_t)l * CC) = __builtin_convertvector(v, h4);
  }
  const size_t o = ((size_t)lc * BB + b) * CC + c4;
  *reinterpret_cast<f4*>(psum + o) = s;
  *reinterpret_cast<f4*>(pmax + o) = m;
}

// ---------------- Kernel 1b: fallback (no fp16 shadow) ----------------
__global__ __launch_bounds__(320) void pool_k(
    const float* __restrict__ x, float* __restrict__ psum,
    float* __restrict__ pmax) {
  const int lc = blockIdx.x;
  const int b  = blockIdx.y;
  const int c4 = threadIdx.x << 2;

  const float* xp = x + ((size_t)b * LL + (size_t)lc * LST) * CC + c4;
  f4 s = {0.f, 0.f, 0.f, 0.f};
  f4 m = {-INFINITY, -INFINITY, -INFINITY, -INFINITY};
#pragma unroll 8
  for (int l = 0; l < LST; ++l) {
    f4 v = *reinterpret_cast<const f4*>(xp + (size_t)l * CC);
    s += v;
    m.x = fmaxf(m.x, v.x); m.y = fmaxf(m.y, v.y);
    m.z = fmaxf(m.z, v.z); m.w = fmaxf(m.w, v.w);
  }
  const size_t o = ((size_t)lc * BB + b) * CC + c4;
  *reinterpret_cast<f4*>(psum + o) = s;
  *reinterpret_cast<f4*>(pmax + o) = m;
}

// ---------------- Kernel 2: finish pools + layer 1 fused ----------------
// grid: 64 blocks (r<32: gap row b=r; r>=32: gmp row b=r-32), block: 320
__global__ __launch_bounds__(320) void finish_l1_k(
    const float* __restrict__ psum, const float* __restrict__ pmax,
    const float* __restrict__ w1, const float* __restrict__ b1,
    float* __restrict__ hout) {
  __shared__ float v[CC];
  __shared__ float part[HH];

  const int r = blockIdx.x;
  const int t = threadIdx.x;
  const int b = r & (BB - 1);
  const bool ismax = (r >= BB);

  for (int c = t; c < CC; c += 320) {
    if (!ismax) {
      float s = 0.f;
      for (int lc = 0; lc < LCH; ++lc)
        s += psum[((size_t)lc * BB + b) * CC + c];
      v[c] = s * (1.0f / (float)LL);
    } else {
      float m = -INFINITY;
      for (int lc = 0; lc < LCH; ++lc)
        m = fmaxf(m, pmax[((size_t)lc * BB + b) * CC + c]);
      v[c] = m;
    }
  }
  __syncthreads();

  const int h  = (t < HH) ? t : t - HH;
  const int k0 = (t < HH) ? 0 : CC / 2;
  float acc = 0.f;
#pragma unroll 8
  for (int k = 0; k < CC / 2; ++k)
    acc = fmaf(v[k0 + k], w1[(size_t)(k0 + k) * HH + h], acc);
  if (t >= HH) part[h] = acc;
  __syncthreads();
  if (t < HH) {
    float a = acc + part[t] + b1[t];
    hout[(size_t)r * HH + t] = fmaxf(a, 0.f);
  }
}

// ---------------- Kernel 3: layer 2 + sigmoid -> attn[B][C] ----------------
__global__ __launch_bounds__(256) void layer2_k(
    const float* __restrict__ hout, const float* __restrict__ w2,
    const float* __restrict__ b2, float* __restrict__ attn) {
  __shared__ float u[HH];
  const int b  = blockIdx.y;
  const int ct = blockIdx.x;
  const int t  = threadIdx.x;

  if (t < HH)
    u[t] = hout[(size_t)b * HH + t] + hout[(size_t)(b + BB) * HH + t];
  __syncthreads();

  const int c = ct * 256 + t;
  float acc = 2.0f * b2[c];
#pragma unroll 8
  for (int h = 0; h < HH; ++h)
    acc = fmaf(u[h], w2[(size_t)h * CC + c], acc);
  attn[(size_t)b * CC + c] = 1.0f / (1.0f + expf(-acc));
}

// ---------------- Kernel 4a: out = fp32(x_h) * attn (x_h expected L3-resident) ----------------
// grid: (B*L/8), block: 320; reverse order matches pool recency; NT stores for out.
__global__ __launch_bounds__(320) void apply_h_k(
    const _Float16* __restrict__ xh, const float* __restrict__ attn,
    float* __restrict__ out) {
  const size_t r0 = (size_t)(gridDim.x - 1 - blockIdx.x) * 8;  // 8 | 2048 -> same b
  const int b = (int)(r0 >> 11);  // L = 2048
  const int c4 = threadIdx.x << 2;

  const f4 a = *reinterpret_cast<const f4*>(attn + (size_t)b * CC + c4);
  const _Float16* hp = xh + r0 * CC + c4;
  float* op = out + r0 * CC + c4;

#pragma unroll
  for (int i = 0; i < 8; ++i) {
    h4 hv = *reinterpret_cast<const h4*>(hp + (size_t)i * CC);
    f4 v = __builtin_convertvector(hv, f4);
    f4 o = v * a;
    __builtin_nontemporal_store(o, reinterpret_cast<f4*>(op + (size_t)i * CC));
  }
}

// ---------------- Kernel 4b: fallback, read fp32 x ----------------
__global__ __launch_bounds__(320) void apply_f_k(
    const float* __restrict__ x, const float* __restrict__ attn,
    float* __restrict__ out) {
  const size_t r0 = (size_t)(gridDim.x - 1 - blockIdx.x) * 8;
  const int b = (int)(r0 >> 11);
  const int c4 = threadIdx.x << 2;

  const f4 a = *reinterpret_cast<const f4*>(attn + (size_t)b * CC + c4);
  const float* xp = x + r0 * CC + c4;
  float* op = out + r0 * CC + c4;

#pragma unroll
  for (int i = 0; i < 8; ++i) {
    f4 v = *reinterpret_cast<const f4*>(xp + (size_t)i * CC);
    f4 o = v * a;
    __builtin_nontemporal_store(o, reinterpret_cast<f4*>(op + (size_t)i * CC));
  }
}

extern "C" void kernel_launch(void* const* d_in, const int* in_sizes, int n_in,
                              void* d_out, int out_size, void* d_ws, size_t ws_size,
                              hipStream_t stream) {
  const float* x  = (const float*)d_in[0];
  const float* w1 = (const float*)d_in[1];
  const float* b1 = (const float*)d_in[2];
  const float* w2 = (const float*)d_in[3];
  const float* b2 = (const float*)d_in[4];
  float* out = (float*)d_out;

  // ws layout: xh[B*L*C] fp16, then psum[LCH][B][C], pmax[LCH][B][C], hout[64][H], attn[B][C]
  const size_t n_x = (size_t)BB * LL * CC;
  const size_t f32_elems = (size_t)LCH * BB * CC * 2 + (size_t)2 * BB * HH + (size_t)BB * CC;
  const bool use_h = ws_size >= n_x * sizeof(_Float16) + f32_elems * sizeof(float);

  _Float16* xh = (_Float16*)d_ws;
  float* fbase = use_h ? (float*)((char*)d_ws + n_x * sizeof(_Float16)) : (float*)d_ws;
  float* psum = fbase;
  float* pmax = psum + (size_t)LCH * BB * CC;
  float* hout = pmax + (size_t)LCH * BB * CC;
  float* attn = hout + (size_t)2 * BB * HH;

  if (use_h)
    pool_conv_k<<<dim3(LCH, BB), 320, 0, stream>>>(x, psum, pmax, xh);
  else
    pool_k<<<dim3(LCH, BB), 320, 0, stream>>>(x, psum, pmax);

  finish_l1_k<<<2 * BB, 320, 0, stream>>>(psum, pmax, w1, b1, hout);
  layer2_k<<<dim3(CC / 256, BB), 256, 0, stream>>>(hout, w2, b2, attn);

  if (use_h)
    apply_h_k<<<BB * LL / 8, 320, 0, stream>>>(xh, attn, out);
  else
    apply_f_k<<<BB * LL / 8, 320, 0, stream>>>(x, attn, out);
}